// Round 1
// baseline (991.504 us; speedup 1.0000x reference)
//
#include <hip/hip_runtime.h>

#define B_ 32
#define S_ 2048
#define D_ 128

typedef __bf16 bf16;
typedef __attribute__((ext_vector_type(8))) __bf16 bf16x8;
typedef __attribute__((ext_vector_type(16))) float f32x16;

__device__ __forceinline__ f32x16 mfma32(bf16x8 a, bf16x8 b, f32x16 c) {
  return __builtin_amdgcn_mfma_f32_32x32x16_bf16(a, b, c, 0, 0, 0);
}

__device__ __forceinline__ unsigned pk2(bf16 a, bf16 b) {
  unsigned short ua = __builtin_bit_cast(unsigned short, a);
  unsigned short ub = __builtin_bit_cast(unsigned short, b);
  return (unsigned)ua | ((unsigned)ub << 16);
}

// ---------------------------------------------------------------------------
// Pre-pass: V [B][S][D] fp32  ->  VT hi/lo bf16 [B][D][S], with the attention
// kernel's LDS read swizzle pre-baked per 64-k chunk:
//   k-block (8 bf16 = 16B) index b' = b ^ (d & 7)
// ---------------------------------------------------------------------------
__global__ __launch_bounds__(256) void vt_prepass(const float* __restrict__ V,
                                                  bf16* __restrict__ vthi,
                                                  bf16* __restrict__ vtlo) {
  const int bid = blockIdx.x;
  const int b = bid >> 5;          // 32 k-tiles per batch
  const int kt = bid & 31;
  const int kbase = kt * 64;
  const int t = threadIdx.x;

  __shared__ __align__(16) bf16 Thi[128][66];  // [d][k], padded rows
  __shared__ __align__(16) bf16 Tlo[128][66];

  // phase 1: coalesced read of V tile, transpose into LDS as hi/lo
  {
    const int dc = t & 31;          // d-group (4 d's)
    const int kr0 = t >> 5;         // 8 rows per pass
#pragma unroll
    for (int i = 0; i < 8; ++i) {
      const int kr = kr0 + i * 8;
      const float* src = V + ((size_t)b * S_ + kbase + kr) * D_ + dc * 4;
      float4 v = *(const float4*)src;
      float f[4] = {v.x, v.y, v.z, v.w};
#pragma unroll
      for (int j = 0; j < 4; ++j) {
        bf16 hi = (bf16)f[j];
        Thi[dc * 4 + j][kr] = hi;
        Tlo[dc * 4 + j][kr] = (bf16)(f[j] - (float)hi);
      }
    }
  }
  __syncthreads();
  // phase 2: each thread owns one d-row (hi or lo), writes 128B contiguous,
  // 16B blocks permuted by the swizzle.
  {
    const int d = t >> 1;
    const int part = t & 1;
    const bf16(*Tp)[66] = part ? Tlo : Thi;
    bf16* dst = part ? vtlo : vthi;
    const unsigned* row = (const unsigned*)(&Tp[d][0]);
    unsigned wbuf[32];
#pragma unroll
    for (int i = 0; i < 32; ++i) wbuf[i] = row[i];
    const size_t rowbase = ((size_t)b * D_ + d) * S_ + kbase;
#pragma unroll
    for (int j = 0; j < 8; ++j) {
      const int jj = j ^ (d & 7);
      uint4 val;
      val.x = wbuf[4 * j + 0];
      val.y = wbuf[4 * j + 1];
      val.z = wbuf[4 * j + 2];
      val.w = wbuf[4 * j + 3];
      *(uint4*)(dst + rowbase + jj * 8) = val;
    }
  }
}

// ---------------------------------------------------------------------------
// Flash attention, 4 waves x 32 q-rows = 128 q per block, KV tile = 64.
// Swapped QK^T (S^T = mfma(K, Q)) so softmax is lane-local; PV computes
// O^T = mfma(VT, P^T). hi/lo bf16 splits give ~fp32 accuracy.
// LDS (dynamic, 72KB): Khi 16K | Klo 16K | VThi 16K | VTlo 16K | mask8 8K
// ---------------------------------------------------------------------------
__global__ __launch_bounds__(256, 2) void attn_kernel(
    const float* __restrict__ Q, const float* __restrict__ K,
    const int* __restrict__ M, const bf16* __restrict__ vthi_g,
    const bf16* __restrict__ vtlo_g, float* __restrict__ Out) {
  extern __shared__ char smem[];
  unsigned* MaskW = (unsigned*)(smem + 65536);

  const int t = threadIdx.x;
  const int w = t >> 6;        // wave id 0..3
  const int i31 = t & 31;      // lane & 31
  const int h = (t >> 5) & 1;  // lane >> 5

  // XCD-aware swizzle: batch b lives on one XCD (K/V L2 reuse)
  const int bid = blockIdx.x;
  const int xcd = bid & 7;
  const int slot = bid >> 3;
  const int b = xcd * 4 + (slot >> 4);
  const int qt = slot & 15;
  const int qbase = qt * 128;

  // ---- Q fragments in registers (scale folded, hi/lo split) ----
  const int qrow = qbase + w * 32 + i31;
  const float* qsrc = Q + ((size_t)b * S_ + qrow) * D_;
  const float sc = 0.08838834764831843f;  // 1/sqrt(128)
  bf16x8 qh[8], ql[8];
#pragma unroll
  for (int ds = 0; ds < 8; ++ds) {
    const int d0 = ds * 16 + h * 8;
    float4 a = *(const float4*)(qsrc + d0);
    float4 c = *(const float4*)(qsrc + d0 + 4);
    float f[8] = {a.x, a.y, a.z, a.w, c.x, c.y, c.z, c.w};
#pragma unroll
    for (int e = 0; e < 8; ++e) {
      float v = f[e] * sc;
      bf16 hi = (bf16)v;
      qh[ds][e] = hi;
      ql[ds][e] = (bf16)(v - (float)hi);
    }
  }

  f32x16 acc[4];
#pragma unroll
  for (int dt = 0; dt < 4; ++dt)
#pragma unroll
    for (int e = 0; e < 16; ++e) acc[dt][e] = 0.f;
  float m_run = -3.0e38f, l_run = 0.f;

  const int qloc = w * 32 + i31;
  const unsigned qsw = (unsigned)(qloc & 15);

  for (int kt = 0; kt < 32; ++kt) {
    const int kbase = kt * 64;
    __syncthreads();  // previous tile fully consumed

    // ---- stage K tile fp32 -> hi/lo bf16, XOR-swizzled ----
    {
      const int kr = t >> 2;
      const int db = (t & 3) * 32;
      const float* src = K + ((size_t)b * S_ + kbase + kr) * D_ + db;
      const unsigned rowb = (unsigned)kr << 8;
      const unsigned sw = (unsigned)(kr & 7) << 4;
#pragma unroll
      for (int j = 0; j < 4; ++j) {
        float4 a = *(const float4*)(src + j * 8);
        float4 c = *(const float4*)(src + j * 8 + 4);
        float f[8] = {a.x, a.y, a.z, a.w, c.x, c.y, c.z, c.w};
        bf16x8 hi8, lo8;
#pragma unroll
        for (int e = 0; e < 8; ++e) {
          bf16 hi = (bf16)f[e];
          hi8[e] = hi;
          lo8[e] = (bf16)(f[e] - (float)hi);
        }
        const unsigned off = rowb + (((unsigned)((db + 8 * j) * 2)) ^ sw);
        *(bf16x8*)(smem + off) = hi8;          // Khi @ 0
        *(bf16x8*)(smem + 16384 + off) = lo8;  // Klo @ 16K
      }
    }
    // ---- stage mask tile int32 -> packed int8, swizzled ----
    {
      const int q = t >> 1;
      const int kb = (t & 1) * 8;
      const int* src = M + ((size_t)b * S_ + qbase + q) * S_ + kbase + kb * 4;
      const unsigned qs = (unsigned)(q & 15);
#pragma unroll
      for (int i = 0; i < 8; ++i) {
        int4 mm = *(const int4*)(src + i * 4);
        unsigned packed = (unsigned)(mm.x & 1) | ((unsigned)(mm.y & 1) << 8) |
                          ((unsigned)(mm.z & 1) << 16) |
                          ((unsigned)(mm.w & 1) << 24);
        MaskW[(unsigned)q * 16 + (((unsigned)(kb + i)) ^ qs)] = packed;
      }
    }
    // ---- stage VT tiles (pre-swizzled in global: linear copy) ----
    {
#pragma unroll
      for (int u = 0; u < 4; ++u) {
        const int off = u * 4096 + t * 16;           // byte in 16KB tile
        const int d = off >> 7;                      // 128B per d-row
        const int bk = (off >> 4) & 7;               // 16B block in row
        const size_t g = ((size_t)b * D_ + d) * S_ + kbase + bk * 8;
        *(bf16x8*)(smem + 32768 + off) = *(const bf16x8*)(vthi_g + g);
        *(bf16x8*)(smem + 49152 + off) = *(const bf16x8*)(vtlo_g + g);
      }
    }
    __syncthreads();

    // ---- QK^T: S^T[k][q], hi*hi + lo*hi + hi*lo ----
    f32x16 s[2];
#pragma unroll
    for (int ct = 0; ct < 2; ++ct)
#pragma unroll
      for (int e = 0; e < 16; ++e) s[ct][e] = 0.f;
#pragma unroll
    for (int ct = 0; ct < 2; ++ct) {
      const unsigned rowb = (unsigned)(ct * 32 + i31) << 8;
      const unsigned sw = (unsigned)(i31 & 7) << 4;
#pragma unroll
      for (int ds = 0; ds < 8; ++ds) {
        const unsigned off = rowb + (((unsigned)(ds * 32 + h * 16)) ^ sw);
        bf16x8 kh = *(const bf16x8*)(smem + off);
        bf16x8 kl = *(const bf16x8*)(smem + 16384 + off);
        s[ct] = mfma32(kh, qh[ds], s[ct]);
        s[ct] = mfma32(kl, qh[ds], s[ct]);
        s[ct] = mfma32(kh, ql[ds], s[ct]);
      }
    }

    // ---- mask: s = keep ? s : -1e6 ----
#pragma unroll
    for (int ct = 0; ct < 2; ++ct) {
#pragma unroll
      for (int rr = 0; rr < 4; ++rr) {
        const unsigned k4 = (unsigned)(ct * 8 + rr * 2 + h);
        const unsigned mm = MaskW[(unsigned)qloc * 16 + (k4 ^ qsw)];
#pragma unroll
        for (int rb = 0; rb < 4; ++rb) {
          const int r = rr * 4 + rb;
          s[ct][r] = ((mm >> (rb * 8)) & 1u) ? s[ct][r] : -1.0e6f;
        }
      }
    }

    // ---- online softmax (row = q = i31; other 32 k's live in lane^32) ----
    float mx = -3.0e38f;
#pragma unroll
    for (int ct = 0; ct < 2; ++ct)
#pragma unroll
      for (int r = 0; r < 16; ++r) mx = fmaxf(mx, s[ct][r]);
    mx = fmaxf(mx, __shfl_xor(mx, 32, 64));
    const float m_new = fmaxf(m_run, mx);
    const float alpha = __expf(m_run - m_new);
    float rs = 0.f;
#pragma unroll
    for (int ct = 0; ct < 2; ++ct)
#pragma unroll
      for (int r = 0; r < 16; ++r) {
        const float p = __expf(s[ct][r] - m_new);
        s[ct][r] = p;
        rs += p;
      }
    rs += __shfl_xor(rs, 32, 64);
    l_run = l_run * alpha + rs;
    m_run = m_new;
#pragma unroll
    for (int dt = 0; dt < 4; ++dt) acc[dt] = acc[dt] * alpha;

    // ---- PV: O^T += VT * P^T ; P^T frags built in-register ----
#pragma unroll
    for (int ks = 0; ks < 4; ++ks) {
      const int ct = ks >> 1;
      const int a0 = (ks & 1) * 8;
      unsigned PKh[4], PKl[4];
#pragma unroll
      for (int y = 0; y < 4; ++y) {
        const float p0 = s[ct][a0 + 2 * y];
        const float p1 = s[ct][a0 + 2 * y + 1];
        bf16 h0 = (bf16)p0, h1 = (bf16)p1;
        PKh[y] = pk2(h0, h1);
        PKl[y] = pk2((bf16)(p0 - (float)h0), (bf16)(p1 - (float)h1));
      }
      const unsigned s0h = h ? PKh[0] : PKh[2];
      const unsigned s1h = h ? PKh[1] : PKh[3];
      const unsigned s0l = h ? PKl[0] : PKl[2];
      const unsigned s1l = h ? PKl[1] : PKl[3];
      const unsigned r0h = __shfl_xor(s0h, 32, 64);
      const unsigned r1h = __shfl_xor(s1h, 32, 64);
      const unsigned r0l = __shfl_xor(s0l, 32, 64);
      const unsigned r1l = __shfl_xor(s1l, 32, 64);
      uint4 fh, fl;
      fh.x = h ? r0h : PKh[0];
      fh.y = h ? r1h : PKh[1];
      fh.z = h ? PKh[2] : r0h;
      fh.w = h ? PKh[3] : r1h;
      fl.x = h ? r0l : PKl[0];
      fl.y = h ? r1l : PKl[1];
      fl.z = h ? PKl[2] : r0l;
      fl.w = h ? PKl[3] : r1l;
      bf16x8 pah = __builtin_bit_cast(bf16x8, fh);
      bf16x8 pal = __builtin_bit_cast(bf16x8, fl);
#pragma unroll
      for (int dt = 0; dt < 4; ++dt) {
        const unsigned d = (unsigned)(dt * 32 + i31);
        const unsigned off = d * 128 + ((((unsigned)(ks * 2 + h)) ^ (d & 7)) * 16);
        bf16x8 vh = *(const bf16x8*)(smem + 32768 + off);
        bf16x8 vl = *(const bf16x8*)(smem + 49152 + off);
        acc[dt] = mfma32(vh, pah, acc[dt]);
        acc[dt] = mfma32(vh, pal, acc[dt]);
        acc[dt] = mfma32(vl, pah, acc[dt]);
      }
    }
  }

  // ---- epilogue: normalize, store (rows of O, consecutive d packed) ----
  const float inv_l = 1.0f / l_run;
  float* orow = Out + ((size_t)b * S_ + qbase + w * 32 + i31) * D_;
#pragma unroll
  for (int dt = 0; dt < 4; ++dt) {
#pragma unroll
    for (int rr = 0; rr < 4; ++rr) {
      float4 o;
      o.x = acc[dt][rr * 4 + 0] * inv_l;
      o.y = acc[dt][rr * 4 + 1] * inv_l;
      o.z = acc[dt][rr * 4 + 2] * inv_l;
      o.w = acc[dt][rr * 4 + 3] * inv_l;
      *(float4*)(orow + dt * 32 + rr * 8 + h * 4) = o;
    }
  }
}

extern "C" void kernel_launch(void* const* d_in, const int* in_sizes, int n_in,
                              void* d_out, int out_size, void* d_ws,
                              size_t ws_size, hipStream_t stream) {
  (void)in_sizes; (void)n_in; (void)out_size; (void)ws_size;
  const float* Q = (const float*)d_in[0];
  const float* K = (const float*)d_in[1];
  const float* V = (const float*)d_in[2];
  const int* M = (const int*)d_in[3];
  float* Out = (float*)d_out;

  bf16* vthi = (bf16*)d_ws;                       // 16.78 MB
  bf16* vtlo = vthi + (size_t)B_ * D_ * S_;       // 16.78 MB

  static int attr_set = 0;
  if (!attr_set) {
    hipFuncSetAttribute((const void*)attn_kernel,
                        hipFuncAttributeMaxDynamicSharedMemorySize, 73728);
    attr_set = 1;
  }

  vt_prepass<<<dim3(B_ * (S_ / 64)), dim3(256), 0, stream>>>(V, vthi, vtlo);
  attn_kernel<<<dim3(512), dim3(256), 73728, stream>>>(Q, K, M, vthi, vtlo, Out);
}

// Round 2
// 957.875 us; speedup vs baseline: 1.0351x; 1.0351x over previous
//
#include <hip/hip_runtime.h>

#define B_ 32
#define S_ 2048
#define D_ 128
#define NT 32   // S_/64 kv tiles
#define QB 256  // q rows per block

typedef __bf16 bf16;
typedef unsigned u32;
typedef unsigned long long u64;
typedef __attribute__((ext_vector_type(8))) __bf16 bf16x8;
typedef __attribute__((ext_vector_type(16))) float f32x16;

__device__ __forceinline__ f32x16 mfma32(bf16x8 a, bf16x8 b, f32x16 c) {
  return __builtin_amdgcn_mfma_f32_32x32x16_bf16(a, b, c, 0, 0, 0);
}

__device__ __forceinline__ u32 pk2(bf16 a, bf16 b) {
  unsigned short ua = __builtin_bit_cast(unsigned short, a);
  unsigned short ub = __builtin_bit_cast(unsigned short, b);
  return (u32)ua | ((u32)ub << 16);
}

// ---------------------------------------------------------------------------
// Pre-pass 1: V [B][S][D] fp32 -> VT hi/lo bf16, tile-contiguous layout
// [b][kt][d][64k] with the attention LDS read swizzle pre-baked:
// stored chunk c holds source k-chunk c ^ (d&7). All global writes coalesced.
// ---------------------------------------------------------------------------
__global__ __launch_bounds__(256) void vt_prepass(const float* __restrict__ V,
                                                  bf16* __restrict__ vthi,
                                                  bf16* __restrict__ vtlo) {
  const int bid = blockIdx.x;
  const int b = bid >> 5, kt = bid & 31;
  const int kbase = kt * 64;
  const int t = threadIdx.x;
  __shared__ u32 Tpk[128][67];  // packed (hi | lo<<16), odd word stride

  // phase 1: coalesced V reads, transpose into LDS
  {
    const int dc = t & 31, kr0 = t >> 5;
#pragma unroll
    for (int i = 0; i < 8; ++i) {
      const int kr = kr0 + i * 8;
      float4 v = *(const float4*)(V + ((size_t)b * S_ + kbase + kr) * D_ + dc * 4);
      float f[4] = {v.x, v.y, v.z, v.w};
#pragma unroll
      for (int j = 0; j < 4; ++j) {
        bf16 hi = (bf16)f[j];
        bf16 lo = (bf16)(f[j] - (float)hi);
        Tpk[dc * 4 + j][kr] = pk2(hi, lo);
      }
    }
  }
  __syncthreads();
  // phase 2: 8 consecutive lanes emit one d-row's 128B contiguously
#pragma unroll
  for (int p = 0; p < 4; ++p) {
    const int g = p * 256 + t;
    const int d = g >> 3, c = g & 7;
    const int cs = c ^ (d & 7);
    u32 wv[8];
#pragma unroll
    for (int e = 0; e < 8; ++e) wv[e] = Tpk[d][cs * 8 + e];
    uint4 hi4, lo4;
    u32* hp = (u32*)&hi4;
    u32* lp = (u32*)&lo4;
#pragma unroll
    for (int j = 0; j < 4; ++j) {
      hp[j] = (wv[2 * j] & 0xffffu) | (wv[2 * j + 1] << 16);
      lp[j] = (wv[2 * j] >> 16) | (wv[2 * j + 1] & 0xffff0000u);
    }
    const size_t base = ((size_t)(b * NT + kt) * 128 + d) * 64 + c * 8;
    *(uint4*)(vthi + base) = hi4;
    *(uint4*)(vtlo + base) = lo4;
  }
}

// ---------------------------------------------------------------------------
// Pre-pass 2: mask int32 [B][S][S] -> bit-packed u64 words [B*S][32]
// (bit k%64 of word k/64 = mask != 0). One ballot per 64 ints.
// ---------------------------------------------------------------------------
__global__ __launch_bounds__(256) void mask_pack(const int* __restrict__ M,
                                                 u64* __restrict__ bits) {
  const int wv = threadIdx.x >> 6;
  const int lane = threadIdx.x & 63;
  const size_t gw = (size_t)blockIdx.x * 4 + wv;
#pragma unroll 1
  for (int i = 0; i < 16; ++i) {
    const size_t r = gw * 16 + i;
    const int* src = M + r * S_;
    u64* dst = bits + r * NT;
#pragma unroll 1
    for (int c = 0; c < NT; c += 8) {
      u64 bm[8];
#pragma unroll
      for (int j = 0; j < 8; ++j) {
        const int v = src[(c + j) * 64 + lane];
        bm[j] = __ballot(v != 0);
      }
      if (lane == 0) {
#pragma unroll
        for (int j = 0; j < 8; ++j) dst[c + j] = bm[j];
      }
    }
  }
}

// ---------------------------------------------------------------------------
// K tile: fp32 regs -> hi/lo bf16 in LDS, XOR-swizzled (block ^= kr&7)
// ---------------------------------------------------------------------------
__device__ __forceinline__ void k_convert_write(const float4 (&ka)[4], char* kdst,
                                                int t) {
  const int kr = t >> 3;
  float f[16] = {ka[0].x, ka[0].y, ka[0].z, ka[0].w, ka[1].x, ka[1].y,
                 ka[1].z, ka[1].w, ka[2].x, ka[2].y, ka[2].z, ka[2].w,
                 ka[3].x, ka[3].y, ka[3].z, ka[3].w};
  bf16x8 h8[2], l8[2];
#pragma unroll
  for (int q = 0; q < 2; ++q)
#pragma unroll
    for (int e = 0; e < 8; ++e) {
      float v = f[q * 8 + e];
      bf16 hi = (bf16)v;
      h8[q][e] = hi;
      l8[q][e] = (bf16)(v - (float)hi);
    }
  const u32 blk = (u32)(t & 7) * 2, swz = (u32)(kr & 7);
#pragma unroll
  for (int q = 0; q < 2; ++q) {
    const u32 off = (u32)kr * 256 + (((blk + q) ^ swz) * 16);
    *(bf16x8*)(kdst + off) = h8[q];
    *(bf16x8*)(kdst + 16384 + off) = l8[q];
  }
}

// ---------------------------------------------------------------------------
// Flash attention: 8 waves x 32 q = 256 q per block, KV tile 64, grid 256
// (1 block/CU). Double-buffered LDS 128KB: per buf {Khi,Klo,VThi,VTlo} 16KB.
// Per tile: issue next-tile loads early -> compute QK/softmax/PV -> write
// next buffer -> one barrier. Softmax in log2 domain; mask applied as p=0.
// ---------------------------------------------------------------------------
__global__ __launch_bounds__(512, 2) void attn_kernel(
    const float* __restrict__ Q, const float* __restrict__ K,
    const u64* __restrict__ MB, const bf16* __restrict__ vthi_g,
    const bf16* __restrict__ vtlo_g, float* __restrict__ Out) {
  extern __shared__ char smem[];
  const int t = threadIdx.x;
  const int w = t >> 6;
  const int i31 = t & 31;
  const int h = (t >> 5) & 1;

  const int bid = blockIdx.x;
  const int b = (bid & 7) * 4 + ((bid >> 3) >> 3);  // 4 batches per XCD
  const int qbase = ((bid >> 3) & 7) * QB;
  const int qloc = w * 32 + i31;

  // Q fragments, scale*log2e folded, hi/lo split
  const float sc = 0.08838834764831843f * 1.4426950408889634f;
  bf16x8 qh[8], ql[8];
  {
    const float* qsrc = Q + ((size_t)b * S_ + qbase + qloc) * D_;
#pragma unroll
    for (int ds = 0; ds < 8; ++ds) {
      const int d0 = ds * 16 + h * 8;
      float4 a = *(const float4*)(qsrc + d0);
      float4 c = *(const float4*)(qsrc + d0 + 4);
      float f[8] = {a.x, a.y, a.z, a.w, c.x, c.y, c.z, c.w};
#pragma unroll
      for (int e = 0; e < 8; ++e) {
        float v = f[e] * sc;
        bf16 hi = (bf16)v;
        qh[ds][e] = hi;
        ql[ds][e] = (bf16)(v - (float)hi);
      }
    }
  }

  f32x16 acc[4];
#pragma unroll
  for (int dt = 0; dt < 4; ++dt)
#pragma unroll
    for (int e = 0; e < 16; ++e) acc[dt][e] = 0.f;
  float m_run = -3.0e38f, l_run = 0.f;

  const float* kbat = K + (size_t)b * S_ * D_;
  const bf16* vh_b = vthi_g + (size_t)b * NT * 8192;
  const bf16* vl_b = vtlo_g + (size_t)b * NT * 8192;
  const u64* mrow = MB + ((size_t)b * S_ + qbase + qloc) * NT;

  const int kr = t >> 3;          // k row this thread stages
  const int kcol = (t & 7) * 16;  // d element offset

  // ---- prologue: stage tile 0 into buffer 0 ----
  u64 mcur = mrow[0];
  {
    float4 ka[4];
    const float* ks = kbat + (size_t)kr * D_ + kcol;
#pragma unroll
    for (int j = 0; j < 4; ++j) ka[j] = *(const float4*)(ks + j * 4);
    uint4 vr0 = *(const uint4*)(vh_b + (size_t)t * 8);
    uint4 vr1 = *(const uint4*)(vh_b + (size_t)(512 + t) * 8);
    uint4 vr2 = *(const uint4*)(vl_b + (size_t)t * 8);
    uint4 vr3 = *(const uint4*)(vl_b + (size_t)(512 + t) * 8);
    k_convert_write(ka, smem, t);
    char* vb = smem + 32768;
    *(uint4*)(vb + t * 16) = vr0;
    *(uint4*)(vb + (512 + t) * 16) = vr1;
    *(uint4*)(vb + 16384 + t * 16) = vr2;
    *(uint4*)(vb + 16384 + (512 + t) * 16) = vr3;
  }
  __syncthreads();

  for (int kt = 0; kt < NT; ++kt) {
    const int cb = kt & 1;
    const char* kb = smem + cb * 65536;
    const bool pre = (kt + 1 < NT);
    float4 ka[4];
    uint4 vr0, vr1, vr2, vr3;
    u64 mnxt = 0;
    if (pre) {  // issue next-tile loads; consumed after compute
      const float* ks = kbat + (size_t)(kt + 1) * 64 * D_ + (size_t)kr * D_ + kcol;
#pragma unroll
      for (int j = 0; j < 4; ++j) ka[j] = *(const float4*)(ks + j * 4);
      const size_t tb = (size_t)(kt + 1) * 8192;
      vr0 = *(const uint4*)(vh_b + tb + (size_t)t * 8);
      vr1 = *(const uint4*)(vh_b + tb + (size_t)(512 + t) * 8);
      vr2 = *(const uint4*)(vl_b + tb + (size_t)t * 8);
      vr3 = *(const uint4*)(vl_b + tb + (size_t)(512 + t) * 8);
      mnxt = mrow[kt + 1];
    }

    // ---- QK^T (S^T = K * Q), hi*hi + lo*hi + hi*lo ----
    f32x16 s[2];
#pragma unroll
    for (int ct = 0; ct < 2; ++ct)
#pragma unroll
      for (int e = 0; e < 16; ++e) s[ct][e] = 0.f;
    __builtin_amdgcn_s_setprio(1);
#pragma unroll
    for (int ct = 0; ct < 2; ++ct) {
      const u32 rowb = (u32)(ct * 32 + i31) * 256;
      const u32 sw = (u32)(i31 & 7) << 4;
#pragma unroll
      for (int ds = 0; ds < 8; ++ds) {
        const u32 off = rowb + (((u32)(ds * 32 + h * 16)) ^ sw);
        bf16x8 kh = *(const bf16x8*)(kb + off);
        bf16x8 kl = *(const bf16x8*)(kb + 16384 + off);
        s[ct] = mfma32(kh, qh[ds], s[ct]);
        s[ct] = mfma32(kl, qh[ds], s[ct]);
        s[ct] = mfma32(kh, ql[ds], s[ct]);
      }
    }
    __builtin_amdgcn_s_setprio(0);

    // ---- online softmax (log2 domain); mask -> p = 0 after exp ----
    float mx = -3.0e38f;
#pragma unroll
    for (int ct = 0; ct < 2; ++ct)
#pragma unroll
      for (int r = 0; r < 16; ++r) mx = fmaxf(mx, s[ct][r]);
    mx = fmaxf(mx, __shfl_xor(mx, 32, 64));
    const float m_new = fmaxf(m_run, mx);
    const float alpha = exp2f(m_run - m_new);
    const u32 mw0 = (u32)mcur, mw1 = (u32)(mcur >> 32);
    float rs = 0.f;
#pragma unroll
    for (int ct = 0; ct < 2; ++ct) {
      const u32 mword = ct ? mw1 : mw0;
#pragma unroll
      for (int r = 0; r < 16; ++r) {
        const int pos = (r & 3) + 8 * (r >> 2) + 4 * h;
        float p = exp2f(s[ct][r] - m_new);
        p = ((mword >> pos) & 1u) ? p : 0.f;
        s[ct][r] = p;
        rs += p;
      }
    }
    rs += __shfl_xor(rs, 32, 64);
    l_run = l_run * alpha + rs;
    m_run = m_new;
#pragma unroll
    for (int dt = 0; dt < 4; ++dt) acc[dt] = acc[dt] * alpha;

    // ---- PV: O^T += VT * P^T, P^T frags built in-register ----
    const char* vbc = kb + 32768;
    __builtin_amdgcn_s_setprio(1);
#pragma unroll
    for (int ks = 0; ks < 4; ++ks) {
      const int ct = ks >> 1;
      const int a0 = (ks & 1) * 8;
      u32 PKh[4], PKl[4];
#pragma unroll
      for (int y = 0; y < 4; ++y) {
        const float p0 = s[ct][a0 + 2 * y];
        const float p1 = s[ct][a0 + 2 * y + 1];
        bf16 h0 = (bf16)p0, h1 = (bf16)p1;
        PKh[y] = pk2(h0, h1);
        PKl[y] = pk2((bf16)(p0 - (float)h0), (bf16)(p1 - (float)h1));
      }
      const u32 s0h = h ? PKh[0] : PKh[2];
      const u32 s1h = h ? PKh[1] : PKh[3];
      const u32 s0l = h ? PKl[0] : PKl[2];
      const u32 s1l = h ? PKl[1] : PKl[3];
      const u32 r0h = __shfl_xor(s0h, 32, 64);
      const u32 r1h = __shfl_xor(s1h, 32, 64);
      const u32 r0l = __shfl_xor(s0l, 32, 64);
      const u32 r1l = __shfl_xor(s1l, 32, 64);
      uint4 fh, fl;
      fh.x = h ? r0h : PKh[0];
      fh.y = h ? r1h : PKh[1];
      fh.z = h ? PKh[2] : r0h;
      fh.w = h ? PKh[3] : r1h;
      fl.x = h ? r0l : PKl[0];
      fl.y = h ? r1l : PKl[1];
      fl.z = h ? PKl[2] : r0l;
      fl.w = h ? PKl[3] : r1l;
      bf16x8 pah = __builtin_bit_cast(bf16x8, fh);
      bf16x8 pal = __builtin_bit_cast(bf16x8, fl);
#pragma unroll
      for (int dt = 0; dt < 4; ++dt) {
        const u32 d = (u32)(dt * 32 + i31);
        const u32 off = d * 128 + ((((u32)(ks * 2 + h)) ^ (d & 7)) * 16);
        bf16x8 vh = *(const bf16x8*)(vbc + off);
        bf16x8 vl = *(const bf16x8*)(vbc + 16384 + off);
        acc[dt] = mfma32(vh, pah, acc[dt]);
        acc[dt] = mfma32(vh, pal, acc[dt]);
        acc[dt] = mfma32(vl, pah, acc[dt]);
      }
    }
    __builtin_amdgcn_s_setprio(0);

    // ---- write next tile's staging into the other buffer ----
    if (pre) {
      char* kdst = smem + (cb ^ 1) * 65536;
      k_convert_write(ka, kdst, t);
      char* vb = kdst + 32768;
      *(uint4*)(vb + t * 16) = vr0;
      *(uint4*)(vb + (512 + t) * 16) = vr1;
      *(uint4*)(vb + 16384 + t * 16) = vr2;
      *(uint4*)(vb + 16384 + (512 + t) * 16) = vr3;
    }
    __syncthreads();
    mcur = mnxt;
  }

  // ---- epilogue ----
  const float inv_l = 1.0f / l_run;
  float* orow = Out + ((size_t)b * S_ + qbase + qloc) * D_;
#pragma unroll
  for (int dt = 0; dt < 4; ++dt) {
#pragma unroll
    for (int rr = 0; rr < 4; ++rr) {
      float4 o;
      o.x = acc[dt][rr * 4 + 0] * inv_l;
      o.y = acc[dt][rr * 4 + 1] * inv_l;
      o.z = acc[dt][rr * 4 + 2] * inv_l;
      o.w = acc[dt][rr * 4 + 3] * inv_l;
      *(float4*)(orow + dt * 32 + rr * 8 + h * 4) = o;
    }
  }
}

extern "C" void kernel_launch(void* const* d_in, const int* in_sizes, int n_in,
                              void* d_out, int out_size, void* d_ws,
                              size_t ws_size, hipStream_t stream) {
  (void)in_sizes; (void)n_in; (void)out_size; (void)ws_size;
  const float* Q = (const float*)d_in[0];
  const float* K = (const float*)d_in[1];
  const float* V = (const float*)d_in[2];
  const int* M = (const int*)d_in[3];
  float* Out = (float*)d_out;

  const size_t vt_el = (size_t)B_ * S_ * D_;     // 8.39M elements
  bf16* vthi = (bf16*)d_ws;                      // 16.78 MB
  bf16* vtlo = vthi + vt_el;                     // 16.78 MB
  u64* mbits = (u64*)(vtlo + vt_el);             // 16.78 MB

  static int attr_set = 0;
  if (!attr_set) {
    hipFuncSetAttribute((const void*)attn_kernel,
                        hipFuncAttributeMaxDynamicSharedMemorySize, 131072);
    attr_set = 1;
  }

  vt_prepass<<<dim3(B_ * NT), dim3(256), 0, stream>>>(V, vthi, vtlo);
  mask_pack<<<dim3(1024), dim3(256), 0, stream>>>(M, mbits);
  attn_kernel<<<dim3(256), dim3(512), 131072, stream>>>(Q, K, mbits, vthi, vtlo,
                                                        Out);
}

// Round 4
// 868.907 us; speedup vs baseline: 1.1411x; 1.1024x over previous
//
#include <hip/hip_runtime.h>

#define B_ 32
#define S_ 2048
#define D_ 128
#define NT 32   // S_/64 kv tiles
#define QB 128  // q rows per block

typedef __bf16 bf16;
typedef unsigned u32;
typedef unsigned long long u64;
typedef __attribute__((ext_vector_type(8))) __bf16 bf16x8;
typedef __attribute__((ext_vector_type(16))) float f32x16;

__device__ __forceinline__ f32x16 mfma32(bf16x8 a, bf16x8 b, f32x16 c) {
  return __builtin_amdgcn_mfma_f32_32x32x16_bf16(a, b, c, 0, 0, 0);
}

__device__ __forceinline__ u32 pk2(bf16 a, bf16 b) {
  unsigned short ua = __builtin_bit_cast(unsigned short, a);
  unsigned short ub = __builtin_bit_cast(unsigned short, b);
  return (u32)ua | ((u32)ub << 16);
}

// async global->LDS, 16B per lane; lds dst must be wave-uniform base
__device__ __forceinline__ void glds16(const bf16* g, char* l) {
  __builtin_amdgcn_global_load_lds(
      (const __attribute__((address_space(1))) void*)g,
      (__attribute__((address_space(3))) void*)l, 16, 0, 0);
}

// ---------------------------------------------------------------------------
// K pre-pass: K [B][S][D] fp32 -> hi/lo bf16, tile-contiguous [b*NT+kt][64][128]
// with the attention QK LDS read swizzle pre-baked: source 16B chunk c of row
// kr stored at chunk c ^ (kr & 15). Attn staging is then a pure linear copy.
// ---------------------------------------------------------------------------
__global__ __launch_bounds__(256) void k_prepass(const float* __restrict__ K,
                                                 bf16* __restrict__ khi,
                                                 bf16* __restrict__ klo) {
  const int bid = blockIdx.x;  // = b*NT + kt (K rows are tile-contiguous)
  const int t = threadIdx.x;
  const int kr = t >> 2;
  const int cbase = (t & 3) * 4;
  const float* src = K + (size_t)bid * 8192 + kr * 128;
  bf16* ho = khi + (size_t)bid * 8192 + kr * 128;
  bf16* lo = klo + (size_t)bid * 8192 + kr * 128;
  const int swz = kr & 15;
#pragma unroll
  for (int j = 0; j < 4; ++j) {
    const int c = cbase + j;
    float4 a = *(const float4*)(src + c * 8);
    float4 b2 = *(const float4*)(src + c * 8 + 4);
    float f[8] = {a.x, a.y, a.z, a.w, b2.x, b2.y, b2.z, b2.w};
    bf16x8 h8, l8;
#pragma unroll
    for (int e = 0; e < 8; ++e) {
      bf16 hi = (bf16)f[e];
      h8[e] = hi;
      l8[e] = (bf16)(f[e] - (float)hi);
    }
    *(bf16x8*)(ho + (c ^ swz) * 8) = h8;
    *(bf16x8*)(lo + (c ^ swz) * 8) = l8;
  }
}

// ---------------------------------------------------------------------------
// V pre-pass: V [B][S][D] fp32 -> VT hi/lo bf16, tile-contiguous
// [b*NT+kt][d][64k], source k-chunk c stored at chunk c ^ (d & 7).
// ---------------------------------------------------------------------------
__global__ __launch_bounds__(256) void vt_prepass(const float* __restrict__ V,
                                                  bf16* __restrict__ vthi,
                                                  bf16* __restrict__ vtlo) {
  const int bid = blockIdx.x;
  const int b = bid >> 5, kt = bid & 31;
  const int kbase = kt * 64;
  const int t = threadIdx.x;
  __shared__ u32 Tpk[128][67];  // packed (hi | lo<<16), odd word stride

  {
    const int dc = t & 31, kr0 = t >> 5;
#pragma unroll
    for (int i = 0; i < 8; ++i) {
      const int kr = kr0 + i * 8;
      float4 v = *(const float4*)(V + ((size_t)b * S_ + kbase + kr) * D_ + dc * 4);
      float f[4] = {v.x, v.y, v.z, v.w};
#pragma unroll
      for (int j = 0; j < 4; ++j) {
        bf16 hi = (bf16)f[j];
        bf16 lo = (bf16)(f[j] - (float)hi);
        Tpk[dc * 4 + j][kr] = pk2(hi, lo);
      }
    }
  }
  __syncthreads();
#pragma unroll
  for (int p = 0; p < 4; ++p) {
    const int g = p * 256 + t;
    const int d = g >> 3, c = g & 7;
    const int cs = c ^ (d & 7);
    u32 wv[8];
#pragma unroll
    for (int e = 0; e < 8; ++e) wv[e] = Tpk[d][cs * 8 + e];
    uint4 hi4, lo4;
    u32* hp = (u32*)&hi4;
    u32* lp = (u32*)&lo4;
#pragma unroll
    for (int j = 0; j < 4; ++j) {
      hp[j] = (wv[2 * j] & 0xffffu) | (wv[2 * j + 1] << 16);
      lp[j] = (wv[2 * j] >> 16) | (wv[2 * j + 1] & 0xffff0000u);
    }
    const size_t base = ((size_t)(b * NT + kt) * 128 + d) * 64 + c * 8;
    *(uint4*)(vthi + base) = hi4;
    *(uint4*)(vtlo + base) = lo4;
  }
}

// ---------------------------------------------------------------------------
// Flash attention: 4 waves x 32 q = 128 q/block, KV tile 64, grid 512 =
// 2 blocks/CU (64KB LDS each) so one block computes while the other drains
// its staging barrier. All K/V staging via global_load_lds (zero VGPR).
// Mask fused: per-tile 32 coalesced dword loads + 32 ballots -> per-lane u64.
// LDS: Khi 16K | Klo 16K | VThi 16K | VTlo 16K (single buffer).
// ---------------------------------------------------------------------------
__global__ __launch_bounds__(256, 2) void attn_kernel(
    const float* __restrict__ Q, const int* __restrict__ M,
    const bf16* __restrict__ khi_g, const bf16* __restrict__ klo_g,
    const bf16* __restrict__ vthi_g, const bf16* __restrict__ vtlo_g,
    float* __restrict__ Out) {
  extern __shared__ char smem[];
  const int t = threadIdx.x;
  const int w = t >> 6;        // wave 0..3
  const int lane = t & 63;
  const int i31 = t & 31;
  const int h = (t >> 5) & 1;

  // XCD swizzle: 512 blocks, 64 per XCD, 4 batches per XCD
  const int bid = blockIdx.x;
  const int idx = bid >> 3;
  const int b = (bid & 7) * 4 + (idx >> 4);
  const int qbase = (idx & 15) * QB;
  const int qloc = w * 32 + i31;

  // ---- Q fragments (scale*log2e folded, hi/lo split) ----
  const float sc = 0.08838834764831843f * 1.4426950408889634f;
  bf16x8 qh[8], ql[8];
  {
    const float* qsrc = Q + ((size_t)b * S_ + qbase + qloc) * D_;
#pragma unroll
    for (int ds = 0; ds < 8; ++ds) {
      const int d0 = ds * 16 + h * 8;
      float4 a = *(const float4*)(qsrc + d0);
      float4 c = *(const float4*)(qsrc + d0 + 4);
      float f[8] = {a.x, a.y, a.z, a.w, c.x, c.y, c.z, c.w};
#pragma unroll
      for (int e = 0; e < 8; ++e) {
        float v = f[e] * sc;
        bf16 hi = (bf16)v;
        qh[ds][e] = hi;
        ql[ds][e] = (bf16)(v - (float)hi);
      }
    }
  }

  f32x16 acc[4];
#pragma unroll
  for (int dt = 0; dt < 4; ++dt)
#pragma unroll
    for (int e = 0; e < 16; ++e) acc[dt][e] = 0.f;
  float m_run = -3.0e38f, l_run = 0.f;

  // wave w stages region w: 0=Khi 1=Klo 2=VThi 3=VTlo (16KB each, 16 glds)
  const bf16* g0 = (w & 2) ? vthi_g : khi_g;
  const bf16* g1 = (w & 2) ? vtlo_g : klo_g;
  const bf16* gsel = (w & 1) ? g1 : g0;
  const size_t tstride = 8192;  // elements per tile region
  const bf16* gsrc0 = gsel + (size_t)(b * NT) * tstride + lane * 8;
  char* ldst = smem + w * 16384;

  // mask row pointer (lane = k column within tile)
  const int* mptr = M + ((size_t)b * S_ + qbase + w * 32) * S_ + lane;

  // ---- prologue: stage tile 0, load tile-0 mask words ----
#pragma unroll
  for (int i = 0; i < 16; ++i) glds16(gsrc0 + i * 512, ldst + i * 1024);
  int mv[32];
#pragma unroll
  for (int r = 0; r < 32; ++r) mv[r] = mptr[r * S_];
  __syncthreads();  // drains glds

  for (int kt = 0; kt < NT; ++kt) {
    // ---- build per-lane mask bits for this tile (ballots) ----
    u64 mc = 0;
#pragma unroll
    for (int r = 0; r < 32; ++r) {
      const u64 bal = __ballot(mv[r] != 0);
      if (i31 == r) mc = bal;
    }
    // ---- issue next tile's mask loads (consumed next iteration) ----
    {
      const int knb = ((kt + 1 < NT) ? kt + 1 : kt) * 64;
#pragma unroll
      for (int r = 0; r < 32; ++r) mv[r] = mptr[r * S_ + knb];
    }

    // ---- QK^T (S^T = K * Q): hi*hi + lo*hi + hi*lo ----
    f32x16 s[2];
#pragma unroll
    for (int ct = 0; ct < 2; ++ct)
#pragma unroll
      for (int e = 0; e < 16; ++e) s[ct][e] = 0.f;
    __builtin_amdgcn_s_setprio(1);
#pragma unroll
    for (int ct = 0; ct < 2; ++ct) {
      const u32 rowb = (u32)(ct * 32 + i31) * 256;
      const u32 sw = (u32)(i31 & 15);
#pragma unroll
      for (int ds = 0; ds < 8; ++ds) {
        const u32 off = rowb + (((u32)(ds * 2 + h) ^ sw) * 16);
        bf16x8 kh = *(const bf16x8*)(smem + off);
        bf16x8 kl = *(const bf16x8*)(smem + 16384 + off);
        s[ct] = mfma32(kh, qh[ds], s[ct]);
        s[ct] = mfma32(kl, qh[ds], s[ct]);
        s[ct] = mfma32(kh, ql[ds], s[ct]);
      }
    }
    __builtin_amdgcn_s_setprio(0);

    // ---- online softmax (log2 domain); mask -> p = 0 after exp ----
    float mx = -3.0e38f;
#pragma unroll
    for (int ct = 0; ct < 2; ++ct)
#pragma unroll
      for (int r = 0; r < 16; ++r) mx = fmaxf(mx, s[ct][r]);
    mx = fmaxf(mx, __shfl_xor(mx, 32, 64));
    const float m_new = fmaxf(m_run, mx);
    const float alpha = exp2f(m_run - m_new);
    const u32 mw0 = (u32)mc, mw1 = (u32)(mc >> 32);
    float rs = 0.f;
#pragma unroll
    for (int ct = 0; ct < 2; ++ct) {
      const u32 mword = ct ? mw1 : mw0;
#pragma unroll
      for (int r = 0; r < 16; ++r) {
        const int pos = (r & 3) + 8 * (r >> 2) + 4 * h;
        float p = exp2f(s[ct][r] - m_new);
        p = ((mword >> pos) & 1u) ? p : 0.f;
        s[ct][r] = p;
        rs += p;
      }
    }
    rs += __shfl_xor(rs, 32, 64);
    l_run = l_run * alpha + rs;
    m_run = m_new;
#pragma unroll
    for (int dt = 0; dt < 4; ++dt) acc[dt] = acc[dt] * alpha;

    // ---- PV: O^T += VT * P^T, P^T frags built in-register ----
    __builtin_amdgcn_s_setprio(1);
#pragma unroll
    for (int ks = 0; ks < 4; ++ks) {
      const int ct = ks >> 1;
      const int a0 = (ks & 1) * 8;
      u32 PKh[4], PKl[4];
#pragma unroll
      for (int y = 0; y < 4; ++y) {
        const float p0 = s[ct][a0 + 2 * y];
        const float p1 = s[ct][a0 + 2 * y + 1];
        bf16 h0 = (bf16)p0, h1 = (bf16)p1;
        PKh[y] = pk2(h0, h1);
        PKl[y] = pk2((bf16)(p0 - (float)h0), (bf16)(p1 - (float)h1));
      }
      const u32 s0h = h ? PKh[0] : PKh[2];
      const u32 s1h = h ? PKh[1] : PKh[3];
      const u32 s0l = h ? PKl[0] : PKl[2];
      const u32 s1l = h ? PKl[1] : PKl[3];
      const u32 r0h = __shfl_xor(s0h, 32, 64);
      const u32 r1h = __shfl_xor(s1h, 32, 64);
      const u32 r0l = __shfl_xor(s0l, 32, 64);
      const u32 r1l = __shfl_xor(s1l, 32, 64);
      uint4 fh, fl;
      fh.x = h ? r0h : PKh[0];
      fh.y = h ? r1h : PKh[1];
      fh.z = h ? PKh[2] : r0h;
      fh.w = h ? PKh[3] : r1h;
      fl.x = h ? r0l : PKl[0];
      fl.y = h ? r1l : PKl[1];
      fl.z = h ? PKl[2] : r0l;
      fl.w = h ? PKl[3] : r1l;
      bf16x8 pah = __builtin_bit_cast(bf16x8, fh);
      bf16x8 pal = __builtin_bit_cast(bf16x8, fl);
#pragma unroll
      for (int dt = 0; dt < 4; ++dt) {
        const u32 d = (u32)(dt * 32 + i31);
        const u32 off = d * 128 + ((((u32)(ks * 2 + h)) ^ (d & 7)) * 16);
        bf16x8 vh = *(const bf16x8*)(smem + 32768 + off);
        bf16x8 vl = *(const bf16x8*)(smem + 49152 + off);
        acc[dt] = mfma32(vh, pah, acc[dt]);
        acc[dt] = mfma32(vh, pal, acc[dt]);
        acc[dt] = mfma32(vl, pah, acc[dt]);
      }
    }
    __builtin_amdgcn_s_setprio(0);

    // ---- restage: all readers done -> async-copy next tile -> visible ----
    __syncthreads();
    if (kt + 1 < NT) {
      const bf16* gsrc = gsrc0 + (size_t)(kt + 1) * tstride;
#pragma unroll
      for (int i = 0; i < 16; ++i) glds16(gsrc + i * 512, ldst + i * 1024);
    }
    __syncthreads();  // implicit vmcnt(0) drains glds
  }

  // ---- epilogue ----
  const float inv_l = 1.0f / l_run;
  float* orow = Out + ((size_t)b * S_ + qbase + qloc) * D_;
#pragma unroll
  for (int dt = 0; dt < 4; ++dt) {
#pragma unroll
    for (int rr = 0; rr < 4; ++rr) {
      float4 o;
      o.x = acc[dt][rr * 4 + 0] * inv_l;
      o.y = acc[dt][rr * 4 + 1] * inv_l;
      o.z = acc[dt][rr * 4 + 2] * inv_l;
      o.w = acc[dt][rr * 4 + 3] * inv_l;
      *(float4*)(orow + dt * 32 + rr * 8 + h * 4) = o;
    }
  }
}

extern "C" void kernel_launch(void* const* d_in, const int* in_sizes, int n_in,
                              void* d_out, int out_size, void* d_ws,
                              size_t ws_size, hipStream_t stream) {
  (void)in_sizes; (void)n_in; (void)out_size; (void)ws_size;
  const float* Q = (const float*)d_in[0];
  const float* K = (const float*)d_in[1];
  const float* V = (const float*)d_in[2];
  const int* M = (const int*)d_in[3];
  float* Out = (float*)d_out;

  const size_t el = (size_t)B_ * S_ * D_;  // 8.39M
  bf16* khi = (bf16*)d_ws;                 // 16.78 MB each
  bf16* klo = khi + el;
  bf16* vthi = klo + el;
  bf16* vtlo = vthi + el;

  static int attr_set = 0;
  if (!attr_set) {
    hipFuncSetAttribute((const void*)attn_kernel,
                        hipFuncAttributeMaxDynamicSharedMemorySize, 65536);
    attr_set = 1;
  }

  k_prepass<<<dim3(B_ * NT), dim3(256), 0, stream>>>(K, khi, klo);
  vt_prepass<<<dim3(B_ * NT), dim3(256), 0, stream>>>(V, vthi, vtlo);
  attn_kernel<<<dim3(512), dim3(256), 65536, stream>>>(Q, M, khi, klo, vthi,
                                                       vtlo, Out);
}